// Round 2
// baseline (305.285 us; speedup 1.0000x reference)
//
#include <hip/hip_runtime.h>
#include <math.h>

#define BB 32
#define SS 512
#define HH 768
#define FDD 64
#define PP 30

// ws float offsets
#define O_TEXT   0u        // 16384*30
#define O_AUDIO  491520u   // 16384*30
#define O_SUMSQ  983040u   // 1 (padded)
#define O_ATT    983072u   // 32*512
#define O_FPART  999456u   // 2*32*768
#define O_WDT    1048608u  // 768*768
// total 1,638,432 floats = 6.55 MB of ws

__device__ __forceinline__ float d4(const float4& a, const float4& b){
  return a.x*b.x + a.y*b.y + a.z*b.z + a.w*b.w;
}

// ---- prep: transpose W_dense into ws, zero sumsq ----
__global__ __launch_bounds__(256) void k_prep(const float* __restrict__ Wd, float* __restrict__ ws){
  int idx = blockIdx.x*256 + threadIdx.x;
  if (idx == 0) ws[O_SUMSQ] = 0.0f;
  if (idx < HH*HH){
    int r = idx / HH, c = idx - r*HH;
    ws[O_WDT + (size_t)c*HH + r] = Wd[idx];
  }
}

// ---- projection: text = HS@Wt^T, audio = AD@Wa^T, + sum(text^2) ----
// one wave handles 2 rows; block = 4 waves = 8 rows
__global__ __launch_bounds__(256) void k_proj(const float* __restrict__ hs, const float* __restrict__ ad,
                                              const float* __restrict__ Wt, const float* __restrict__ Wa,
                                              float* __restrict__ ws){
  const int tid = threadIdx.x;
  const int wave = tid >> 6, lane = tid & 63;
  const int row = blockIdx.x*8 + wave*2;
  const float4* h0 = (const float4*)(hs + (size_t)row*HH);
  const float4* h1 = (const float4*)(hs + (size_t)(row+1)*HH);
  float4 ra0 = h0[lane], ra1 = h0[lane+64], ra2 = h0[lane+128];
  float4 rb0 = h1[lane], rb1 = h1[lane+64], rb2 = h1[lane+128];
  float aa = ad[(size_t)row*FDD + lane];
  float ab = ad[(size_t)(row+1)*FDD + lane];
  float* text  = ws + O_TEXT;
  float* audio = ws + O_AUDIO;
  float sq = 0.0f;
  for (int p = 0; p < PP; ++p){
    const float4* w4 = (const float4*)(Wt + (size_t)p*HH);
    float4 w0 = w4[lane], w1 = w4[lane+64], w2 = w4[lane+128];
    float ta = d4(ra0,w0) + d4(ra1,w1) + d4(ra2,w2);
    float tb = d4(rb0,w0) + d4(rb1,w1) + d4(rb2,w2);
    float wa = Wa[p*FDD + lane];
    float ua = aa*wa, ub = ab*wa;
    #pragma unroll
    for (int off = 32; off > 0; off >>= 1){
      ta += __shfl_xor(ta, off);
      tb += __shfl_xor(tb, off);
      ua += __shfl_xor(ua, off);
      ub += __shfl_xor(ub, off);
    }
    if (lane == 0){
      text[(size_t)row*PP + p]       = ta;
      text[(size_t)(row+1)*PP + p]   = tb;
      audio[(size_t)row*PP + p]      = ua;
      audio[(size_t)(row+1)*PP + p]  = ub;
    }
    sq += ta*ta + tb*tb;   // identical across lanes after butterfly
  }
  __shared__ float wred[4];
  if (lane == 0) wred[wave] = sq;
  __syncthreads();
  if (tid == 0) atomicAdd(ws + O_SUMSQ, wred[0]+wred[1]+wred[2]+wred[3]);
}

// ---- gram: text_att1 / fusion_att1 outputs, 64x64 tile, 4x4 per thread ----
__global__ __launch_bounds__(256) void k_gram(const float* __restrict__ ws,
    const float* __restrict__ twp, const float* __restrict__ awp, const float* __restrict__ fbp,
    float* __restrict__ out_text, float* __restrict__ out_fus){
  __shared__ __align__(16) float L[4*PP*68];
  float* LtS = L;
  float* LtT = L +   PP*68;
  float* LaS = L + 2*PP*68;
  float* LaT = L + 3*PP*68;
  const int tid = threadIdx.x;
  const int tb = blockIdx.x, sb = blockIdx.y, b = blockIdx.z;
  const float* text  = ws + O_TEXT;
  const float* audio = ws + O_AUDIO;
  const size_t baseS = ((size_t)b*SS + sb*64)*PP;
  const size_t baseT = ((size_t)b*SS + tb*64)*PP;
  for (int j = tid; j < 64*PP; j += 256){
    int sl = j / PP, p = j - sl*PP;
    LtS[p*68 + sl] = text[baseS + j];
    LtT[p*68 + sl] = text[baseT + j];
    LaS[p*68 + sl] = audio[baseS + j];
    LaT[p*68 + sl] = audio[baseT + j];
  }
  __syncthreads();
  const float inv_s = 1.0f / sqrtf(ws[O_SUMSQ]);   // scales text dot products
  const float tw = twp[0], aw = awp[0], fb = fbp[0];
  const int tx = tid & 15, ty = tid >> 4;
  float tacc[4][4] = {{0.f}};
  float aacc[4][4] = {{0.f}};
  #pragma unroll
  for (int p = 0; p < PP; ++p){
    const float4 ts  = *(const float4*)&LtS[p*68 + ty*4];
    const float4 tt  = *(const float4*)&LtT[p*68 + tx*4];
    const float4 as_ = *(const float4*)&LaS[p*68 + ty*4];
    const float4 at_ = *(const float4*)&LaT[p*68 + tx*4];
    const float tsv[4] = {ts.x,ts.y,ts.z,ts.w};
    const float ttv[4] = {tt.x,tt.y,tt.z,tt.w};
    const float asv[4] = {as_.x,as_.y,as_.z,as_.w};
    const float atv[4] = {at_.x,at_.y,at_.z,at_.w};
    #pragma unroll
    for (int i=0;i<4;i++){
      #pragma unroll
      for (int j=0;j<4;j++){
        tacc[i][j] += tsv[i]*ttv[j];
        aacc[i][j] += asv[i]*atv[j];
      }
    }
  }
  const int s_out = sb*64 + ty*4;
  const int t_out = tb*64 + tx*4;
  #pragma unroll
  for (int i=0;i<4;i++){
    float vt[4], vf[4];
    #pragma unroll
    for (int j=0;j<4;j++){
      float tr_ = fmaxf(tacc[i][j]*inv_s, 0.0f);
      float ar_ = fmaxf(aacc[i][j], 0.0f);
      vt[j] = tr_;
      vf[j] = fmaxf(tw*tr_ + aw*ar_ + fb, 0.0f);
    }
    size_t o = ((size_t)b*SS + (size_t)(s_out+i))*SS + t_out;
    *(float4*)(out_text + o) = make_float4(vt[0],vt[1],vt[2],vt[3]);
    *(float4*)(out_fus  + o) = make_float4(vf[0],vf[1],vf[2],vf[3]);
  }
}

// ---- row-0 softmax per batch ----
__global__ __launch_bounds__(256) void k_att0(float* __restrict__ ws, const float* __restrict__ amask,
    const float* __restrict__ twp, const float* __restrict__ awp, const float* __restrict__ fbp){
  const int b = blockIdx.x, tid = threadIdx.x;
  __shared__ float t0[PP], a0[PP];
  __shared__ float red[256];
  const float* text  = ws + O_TEXT;
  const float* audio = ws + O_AUDIO;
  if (tid < PP){
    t0[tid] = text[(size_t)b*SS*PP + tid];
    a0[tid] = audio[(size_t)b*SS*PP + tid];
  }
  __syncthreads();
  const float inv_s = 1.0f / sqrtf(ws[O_SUMSQ]);
  const float tw = twp[0], aw = awp[0], fb = fbp[0];
  const float m0 = amask[(size_t)b*SS];   // row-constant mask term (cancels, kept for fidelity)
  float sv[2];
  #pragma unroll
  for (int k=0;k<2;k++){
    int t = tid + k*256;
    const float* tr = text  + ((size_t)b*SS + t)*PP;
    const float* ar = audio + ((size_t)b*SS + t)*PP;
    float dt=0.f, da=0.f;
    #pragma unroll
    for (int p=0;p<PP;p++){ dt += t0[p]*tr[p]; da += a0[p]*ar[p]; }
    sv[k] = tw*fmaxf(dt*inv_s,0.f) + aw*fmaxf(da,0.f) + fb
          + amask[(size_t)b*SS + t] + m0;
  }
  red[tid] = fmaxf(sv[0], sv[1]);
  __syncthreads();
  for (int s2=128; s2>0; s2>>=1){ if (tid < s2) red[tid] = fmaxf(red[tid], red[tid+s2]); __syncthreads(); }
  const float m = red[0];
  __syncthreads();
  float e0 = __expf(sv[0]-m), e1 = __expf(sv[1]-m);
  red[tid] = e0 + e1;
  __syncthreads();
  for (int s2=128; s2>0; s2>>=1){ if (tid < s2) red[tid] += red[tid+s2]; __syncthreads(); }
  const float inv = 1.0f / red[0];
  float* att = ws + O_ATT + (size_t)b*SS;
  att[tid]       = e0*inv;
  att[tid + 256] = e1*inv;
}

// ---- row-0 PV: fusion_part = att_row @ HS (+ skip), split over (3 col-chunks, 2 t-halves, 32 b) ----
__global__ __launch_bounds__(256) void k_pv(const float* __restrict__ hs, float* __restrict__ ws){
  const int tid = threadIdx.x;
  const int cx = blockIdx.x, th = blockIdx.y, b = blockIdx.z;
  __shared__ float a[256];
  a[tid] = ws[O_ATT + (size_t)b*SS + th*256 + tid];
  __syncthreads();
  const int c = cx*256 + tid;
  const float* hp = hs + ((size_t)b*SS + th*256)*HH + c;
  float acc = 0.f;
  #pragma unroll 8
  for (int t=0;t<256;t++) acc += a[t]*hp[(size_t)t*HH];
  if (th == 0) acc += hs[(size_t)b*SS*HH + c];   // residual: + HS[b,0,c]
  ws[O_FPART + ((size_t)th*BB + b)*HH + c] = acc;
}

// ---- dense (row 0) + LayerNorm ----
__global__ __launch_bounds__(256) void k_dense_ln(const float* __restrict__ ws,
    const float* __restrict__ bd, const float* __restrict__ lw, const float* __restrict__ lb,
    float* __restrict__ out){
  const int b = blockIdx.x, tid = threadIdx.x;
  __shared__ float f[HH];
  __shared__ float red[256];
  for (int c=tid; c<HH; c+=256)
    f[c] = ws[O_FPART + (size_t)b*HH + c] + ws[O_FPART + (size_t)(BB+b)*HH + c];
  __syncthreads();
  const float* WdT = ws + O_WDT;
  float a0=0.f, a1=0.f, a2=0.f;
  #pragma unroll 4
  for (int c=0;c<HH;c++){
    const float fv = f[c];
    const float* wr = WdT + (size_t)c*HH + tid;
    a0 += fv*wr[0];
    a1 += fv*wr[256];
    a2 += fv*wr[512];
  }
  a0 += bd[tid]; a1 += bd[tid+256]; a2 += bd[tid+512];
  red[tid] = a0+a1+a2;
  __syncthreads();
  for (int s2=128;s2>0;s2>>=1){ if (tid<s2) red[tid]+=red[tid+s2]; __syncthreads(); }
  const float u = red[0] * (1.0f/HH);
  __syncthreads();
  const float d0=a0-u, d1=a1-u, d2=a2-u;
  red[tid] = d0*d0 + d1*d1 + d2*d2;
  __syncthreads();
  for (int s2=128;s2>0;s2>>=1){ if (tid<s2) red[tid]+=red[tid+s2]; __syncthreads(); }
  const float isd = 1.0f / sqrtf(red[0]*(1.0f/HH) + 1e-12f);
  out[(size_t)b*HH + tid]     = lw[tid]    *d0*isd + lb[tid];
  out[(size_t)b*HH + tid+256] = lw[tid+256]*d1*isd + lb[tid+256];
  out[(size_t)b*HH + tid+512] = lw[tid+512]*d2*isd + lb[tid+512];
}

extern "C" void kernel_launch(void* const* d_in, const int* in_sizes, int n_in,
                              void* d_out, int out_size, void* d_ws, size_t ws_size,
                              hipStream_t stream){
  const float* hs    = (const float*)d_in[0];
  const float* ad    = (const float*)d_in[1];
  const float* amask = (const float*)d_in[2];
  const float* Wt    = (const float*)d_in[3];
  const float* Wa    = (const float*)d_in[4];
  const float* twp   = (const float*)d_in[5];
  const float* awp   = (const float*)d_in[6];
  const float* fbp   = (const float*)d_in[7];
  const float* Wd    = (const float*)d_in[8];
  const float* bd    = (const float*)d_in[9];
  const float* lw    = (const float*)d_in[10];
  const float* lb    = (const float*)d_in[11];
  float* out = (float*)d_out;
  float* ws  = (float*)d_ws;
  float* out_h    = out;
  float* out_text = out + (size_t)BB*HH;
  float* out_fus  = out_text + (size_t)BB*SS*SS;

  hipLaunchKernelGGL(k_prep, dim3((HH*HH+255)/256), dim3(256), 0, stream, Wd, ws);
  hipLaunchKernelGGL(k_proj, dim3(BB*SS/8), dim3(256), 0, stream, hs, ad, Wt, Wa, ws);
  hipLaunchKernelGGL(k_gram, dim3(8,8,BB), dim3(256), 0, stream, ws, twp, awp, fbp, out_text, out_fus);
  hipLaunchKernelGGL(k_att0, dim3(BB), dim3(256), 0, stream, ws, amask, twp, awp, fbp);
  hipLaunchKernelGGL(k_pv, dim3(3,2,BB), dim3(256), 0, stream, hs, ws);
  hipLaunchKernelGGL(k_dense_ln, dim3(BB), dim3(256), 0, stream, ws, bd, lw, lb, out_h);
}

// Round 4
// 248.946 us; speedup vs baseline: 1.2263x; 1.2263x over previous
//
#include <hip/hip_runtime.h>
#include <math.h>

#define BB 32
#define SS 512
#define HH 768
#define FDD 64
#define PP 30

typedef __attribute__((ext_vector_type(8))) short short8v;
typedef __attribute__((ext_vector_type(4))) float f32x4;

// ws float offsets
#define O_TEXTF  0u        // fp32 text  [16384][32]
#define O_AUDF   524288u   // fp32 audio [16384][32]
#define O_ATT    1048576u  // 32*512
#define O_FPART  1064960u  // 8*32*768
#define O_WDT    1261568u  // 768*768 transposed W_dense
#define O_WTB    1851392u  // 24576 ushort (bf16 Wt frag-ordered [2][24][64][8])
#define O_WAB    1863680u  // 2048 ushort  (bf16 Wa frag-ordered [2][2][64][8])
#define O_TEXTB  1864704u  // bf16 text  [16384][32] (262144 floats)
#define O_AUDB   2126848u  // bf16 audio [16384][32]
#define O_SUMSQ  2388992u  // 1

__device__ __forceinline__ unsigned short f2bf(float f){
  unsigned u = __float_as_uint(f);
  unsigned r = (u + 0x7fffu + ((u>>16)&1u)) >> 16;   // RNE
  return (unsigned short)r;
}
__device__ __forceinline__ float d4(const float4& a, const float4& b){
  return a.x*b.x + a.y*b.y + a.z*b.z + a.w*b.w;
}

// ---- prep: WdT transpose, bf16 frag-ordered Wt/Wa, zero sumsq ----
__global__ __launch_bounds__(256) void k_prep(const float* __restrict__ Wd,
    const float* __restrict__ Wt, const float* __restrict__ Wa, float* __restrict__ ws){
  int idx = blockIdx.x*256 + threadIdx.x;
  if (idx < HH*HH){
    int r = idx / HH, c = idx - r*HH;
    ws[O_WDT + (size_t)c*HH + r] = Wd[idx];
  } else if (idx < HH*HH + 24576){
    int fi = idx - HH*HH;
    int j = fi & 7, lane = (fi>>3) & 63, t = fi>>9;   // t = n*24+ks
    int n = t / 24, ks = t - n*24;
    int p = n*16 + (lane & 15);
    int k = ks*32 + ((lane>>4)<<3) + j;
    float v = (p < PP) ? Wt[p*HH + k] : 0.0f;
    ((unsigned short*)(ws + O_WTB))[fi] = f2bf(v);
  } else if (idx < HH*HH + 24576 + 2048){
    int fa = idx - (HH*HH + 24576);
    int j = fa & 7, lane = (fa>>3) & 63, t = fa>>9;   // t = n*2+ks
    int n = t>>1, ks = t & 1;
    int p = n*16 + (lane & 15);
    int k = ks*32 + ((lane>>4)<<3) + j;
    float v = (p < PP) ? Wa[p*FDD + k] : 0.0f;
    ((unsigned short*)(ws + O_WAB))[fa] = f2bf(v);
  } else if (idx == HH*HH + 24576 + 2048){
    ws[O_SUMSQ] = 0.0f;
  }
}

// ---- projection via bf16 MFMA: 64 rows/block, 4 waves x 16 rows ----
__global__ __launch_bounds__(256) void k_proj(const float* __restrict__ hs,
    const float* __restrict__ ad, float* __restrict__ ws){
  __shared__ __align__(16) unsigned short Ast[64*32];   // frag-ordered bf16 A tile
  const int tid = threadIdx.x;
  const int lane = tid & 63, w = tid >> 6;
  const int rowbase = blockIdx.x * 64;
  const int tr = tid >> 2, tq = tid & 3;                // staging: row, k-quad
  const int wrunit = ((tr>>4)<<6) + (tr & 15) + (tq<<4);
  const short8v* WTB = (const short8v*)(ws + O_WTB);
  const short8v* WAB = (const short8v*)(ws + O_WAB);
  f32x4 accT0 = {0,0,0,0}, accT1 = {0,0,0,0};

  const float* hsr = hs + (size_t)(rowbase + tr)*HH + tq*8;
  float4 p0 = *(const float4*)hsr, p1 = *(const float4*)(hsr + 4);
  for (int ks = 0; ks < 24; ++ks){
    __syncthreads();   // previous iter's reads done
    uint4 pk;
    pk.x = f2bf(p0.x) | ((unsigned)f2bf(p0.y) << 16);
    pk.y = f2bf(p0.z) | ((unsigned)f2bf(p0.w) << 16);
    pk.z = f2bf(p1.x) | ((unsigned)f2bf(p1.y) << 16);
    pk.w = f2bf(p1.z) | ((unsigned)f2bf(p1.w) << 16);
    *(uint4*)&Ast[wrunit*8] = pk;
    if (ks < 23){ hsr += 32; p0 = *(const float4*)hsr; p1 = *(const float4*)(hsr + 4); }
    __syncthreads();
    short8v a = *(const short8v*)&Ast[(w*64 + lane)*8];
    short8v b0 = WTB[ks*64 + lane];
    short8v b1 = WTB[(24 + ks)*64 + lane];
    accT0 = __builtin_amdgcn_mfma_f32_16x16x32_bf16(a, b0, accT0, 0, 0, 0);
    accT1 = __builtin_amdgcn_mfma_f32_16x16x32_bf16(a, b1, accT1, 0, 0, 0);
  }

  f32x4 accA0 = {0,0,0,0}, accA1 = {0,0,0,0};
  for (int ks = 0; ks < 2; ++ks){
    const float* adr = ad + (size_t)(rowbase + tr)*FDD + ks*32 + tq*8;
    float4 q0 = *(const float4*)adr, q1 = *(const float4*)(adr + 4);
    __syncthreads();
    uint4 pk;
    pk.x = f2bf(q0.x) | ((unsigned)f2bf(q0.y) << 16);
    pk.y = f2bf(q0.z) | ((unsigned)f2bf(q0.w) << 16);
    pk.z = f2bf(q1.x) | ((unsigned)f2bf(q1.y) << 16);
    pk.w = f2bf(q1.z) | ((unsigned)f2bf(q1.w) << 16);
    *(uint4*)&Ast[wrunit*8] = pk;
    __syncthreads();
    short8v a = *(const short8v*)&Ast[(w*64 + lane)*8];
    accA0 = __builtin_amdgcn_mfma_f32_16x16x32_bf16(a, WAB[ks*64 + lane], accA0, 0, 0, 0);
    accA1 = __builtin_amdgcn_mfma_f32_16x16x32_bf16(a, WAB[(2 + ks)*64 + lane], accA1, 0, 0, 0);
  }

  // epilogue: C layout col=lane&15, row=(lane>>4)*4+r
  float* TEXTF = ws + O_TEXTF;
  float* AUDF  = ws + O_AUDF;
  unsigned short* TEXTB = (unsigned short*)(ws + O_TEXTB);
  unsigned short* AUDB  = (unsigned short*)(ws + O_AUDB);
  const int q4 = lane >> 4, pl = lane & 15;
  float sq = 0.0f;
  #pragma unroll
  for (int r = 0; r < 4; ++r){
    int row = rowbase + w*16 + q4*4 + r;
    float v0 = accT0[r], v1 = accT1[r];
    sq += v0*v0 + v1*v1;                    // p=30,31 are exact zeros (zero B cols)
    TEXTF[(size_t)row*32 + pl]      = v0;
    TEXTF[(size_t)row*32 + 16 + pl] = v1;
    TEXTB[(size_t)row*32 + pl]      = f2bf(v0);
    TEXTB[(size_t)row*32 + 16 + pl] = f2bf(v1);
    float a0 = accA0[r], a1 = accA1[r];
    AUDF[(size_t)row*32 + pl]      = a0;
    AUDF[(size_t)row*32 + 16 + pl] = a1;
    AUDB[(size_t)row*32 + pl]      = f2bf(a0);
    AUDB[(size_t)row*32 + 16 + pl] = f2bf(a1);
  }
  #pragma unroll
  for (int off = 32; off; off >>= 1) sq += __shfl_xor(sq, off);
  if (lane == 0) atomicAdd(ws + O_SUMSQ, sq);
}

// ---- gram via bf16 MFMA, K=32 (pad), no LDS; 64x64 tile per block ----
__global__ __launch_bounds__(256) void k_gram(const float* __restrict__ ws,
    const float* __restrict__ twp, const float* __restrict__ awp, const float* __restrict__ fbp,
    float* __restrict__ out_text, float* __restrict__ out_fus){
  const int tid = threadIdx.x, lane = tid & 63, w = tid >> 6;
  const int tt = blockIdx.x, st = blockIdx.y, b = blockIdx.z;
  const unsigned short* TEXTB = (const unsigned short*)(ws + O_TEXTB);
  const unsigned short* AUDB  = (const unsigned short*)(ws + O_AUDB);
  const int q4 = lane >> 4, pl = lane & 15;
  const size_t srow  = (size_t)b*SS + st*64 + w*16 + pl;
  const size_t trow0 = (size_t)b*SS + tt*64 + pl;
  short8v at = *(const short8v*)&TEXTB[srow*32 + q4*8];
  short8v aa = *(const short8v*)&AUDB [srow*32 + q4*8];
  f32x4 z = {0,0,0,0};
  f32x4 ct[4], ca[4];
  #pragma unroll
  for (int n = 0; n < 4; ++n){
    short8v bt = *(const short8v*)&TEXTB[(trow0 + n*16)*32 + q4*8];
    short8v ba = *(const short8v*)&AUDB [(trow0 + n*16)*32 + q4*8];
    ct[n] = __builtin_amdgcn_mfma_f32_16x16x32_bf16(at, bt, z, 0, 0, 0);
    ca[n] = __builtin_amdgcn_mfma_f32_16x16x32_bf16(aa, ba, z, 0, 0, 0);
  }
  const float inv_s = 1.0f / sqrtf(ws[O_SUMSQ]);
  const float tw = twp[0], aw = awp[0], fb = fbp[0];
  #pragma unroll
  for (int n = 0; n < 4; ++n){
    #pragma unroll
    for (int r = 0; r < 4; ++r){
      float t_ = fmaxf(ct[n][r]*inv_s, 0.0f);
      float a_ = fmaxf(ca[n][r], 0.0f);
      float f_ = fmaxf(tw*t_ + aw*a_ + fb, 0.0f);
      int sr = st*64 + w*16 + q4*4 + r;
      int tc = tt*64 + n*16 + pl;
      size_t o = ((size_t)b*SS + sr)*SS + tc;
      out_text[o] = t_;
      out_fus[o]  = f_;
    }
  }
}

// ---- row-0 softmax per batch (fp32 path) ----
__global__ __launch_bounds__(256) void k_att0(float* __restrict__ ws, const float* __restrict__ amask,
    const float* __restrict__ twp, const float* __restrict__ awp, const float* __restrict__ fbp){
  const int b = blockIdx.x, tid = threadIdx.x;
  __shared__ __align__(16) float t0[32], a0[32];
  __shared__ float red[256];
  const float* TEXTF = ws + O_TEXTF;
  const float* AUDF  = ws + O_AUDF;
  if (tid < 32){
    t0[tid] = TEXTF[(size_t)b*SS*32 + tid];
    a0[tid] = AUDF [(size_t)b*SS*32 + tid];
  }
  __syncthreads();
  const float inv_s = 1.0f / sqrtf(ws[O_SUMSQ]);
  const float tw = twp[0], aw = awp[0], fb = fbp[0];
  const float m0 = amask[(size_t)b*SS];
  const float4* t04 = (const float4*)t0;
  const float4* a04 = (const float4*)a0;
  float sv[2];
  #pragma unroll
  for (int k = 0; k < 2; ++k){
    int t = tid + k*256;
    const float4* tr = (const float4*)(TEXTF + ((size_t)b*SS + t)*32);
    const float4* ar = (const float4*)(AUDF  + ((size_t)b*SS + t)*32);
    float dt = 0.f, da = 0.f;
    #pragma unroll
    for (int q = 0; q < 8; ++q){ dt += d4(t04[q], tr[q]); da += d4(a04[q], ar[q]); }
    sv[k] = tw*fmaxf(dt*inv_s, 0.f) + aw*fmaxf(da, 0.f) + fb
          + amask[(size_t)b*SS + t] + m0;
  }
  red[tid] = fmaxf(sv[0], sv[1]);
  __syncthreads();
  for (int s2 = 128; s2 > 0; s2 >>= 1){ if (tid < s2) red[tid] = fmaxf(red[tid], red[tid+s2]); __syncthreads(); }
  const float m = red[0];
  __syncthreads();
  float e0 = __expf(sv[0]-m), e1 = __expf(sv[1]-m);
  red[tid] = e0 + e1;
  __syncthreads();
  for (int s2 = 128; s2 > 0; s2 >>= 1){ if (tid < s2) red[tid] += red[tid+s2]; __syncthreads(); }
  const float inv = 1.0f / red[0];
  float* att = ws + O_ATT + (size_t)b*SS;
  att[tid]       = e0*inv;
  att[tid + 256] = e1*inv;
}

// ---- row-0 PV: (3 c-chunks, 8 t-chunks, 32 b) ----
__global__ __launch_bounds__(256) void k_pv(const float* __restrict__ hs, float* __restrict__ ws){
  const int tid = threadIdx.x;
  const int cx = blockIdx.x, th = blockIdx.y, b = blockIdx.z;
  __shared__ float a[64];
  if (tid < 64) a[tid] = ws[O_ATT + (size_t)b*SS + th*64 + tid];
  __syncthreads();
  const int c = cx*256 + tid;
  const float* hp = hs + ((size_t)b*SS + th*64)*HH + c;
  float acc = 0.f;
  #pragma unroll 8
  for (int t = 0; t < 64; ++t) acc += a[t]*hp[(size_t)t*HH];
  if (th == 0) acc += hs[(size_t)b*SS*HH + c];   // residual
  ws[O_FPART + ((size_t)th*BB + b)*HH + c] = acc;
}

// ---- dense (row 0) + LayerNorm ----
__global__ __launch_bounds__(256) void k_dense_ln(const float* __restrict__ ws,
    const float* __restrict__ bd, const float* __restrict__ lw, const float* __restrict__ lb,
    float* __restrict__ out){
  const int b = blockIdx.x, tid = threadIdx.x;
  __shared__ float f[HH];
  __shared__ float red[256];
  for (int c = tid; c < HH; c += 256){
    float s = 0.f;
    #pragma unroll
    for (int th = 0; th < 8; ++th) s += ws[O_FPART + ((size_t)th*BB + b)*HH + c];
    f[c] = s;
  }
  __syncthreads();
  const float* WdT = ws + O_WDT;
  float a0 = 0.f, a1 = 0.f, a2 = 0.f;
  #pragma unroll 4
  for (int c = 0; c < HH; ++c){
    const float fv = f[c];
    const float* wr = WdT + (size_t)c*HH + tid;
    a0 += fv*wr[0];
    a1 += fv*wr[256];
    a2 += fv*wr[512];
  }
  a0 += bd[tid]; a1 += bd[tid+256]; a2 += bd[tid+512];
  red[tid] = a0 + a1 + a2;
  __syncthreads();
  for (int s2 = 128; s2 > 0; s2 >>= 1){ if (tid < s2) red[tid] += red[tid+s2]; __syncthreads(); }
  const float u = red[0]*(1.0f/HH);
  __syncthreads();
  const float d0 = a0-u, d1 = a1-u, d2 = a2-u;
  red[tid] = d0*d0 + d1*d1 + d2*d2;
  __syncthreads();
  for (int s2 = 128; s2 > 0; s2 >>= 1){ if (tid < s2) red[tid] += red[tid+s2]; __syncthreads(); }
  const float isd = 1.0f / sqrtf(red[0]*(1.0f/HH) + 1e-12f);
  out[(size_t)b*HH + tid]     = lw[tid]    *d0*isd + lb[tid];
  out[(size_t)b*HH + tid+256] = lw[tid+256]*d1*isd + lb[tid+256];
  out[(size_t)b*HH + tid+512] = lw[tid+512]*d2*isd + lb[tid+512];
}

extern "C" void kernel_launch(void* const* d_in, const int* in_sizes, int n_in,
                              void* d_out, int out_size, void* d_ws, size_t ws_size,
                              hipStream_t stream){
  const float* hs    = (const float*)d_in[0];
  const float* ad    = (const float*)d_in[1];
  const float* amask = (const float*)d_in[2];
  const float* Wt    = (const float*)d_in[3];
  const float* Wa    = (const float*)d_in[4];
  const float* twp   = (const float*)d_in[5];
  const float* awp   = (const float*)d_in[6];
  const float* fbp   = (const float*)d_in[7];
  const float* Wd    = (const float*)d_in[8];
  const float* bd    = (const float*)d_in[9];
  const float* lw    = (const float*)d_in[10];
  const float* lb    = (const float*)d_in[11];
  float* out = (float*)d_out;
  float* ws  = (float*)d_ws;
  float* out_h    = out;
  float* out_text = out + (size_t)BB*HH;
  float* out_fus  = out_text + (size_t)BB*SS*SS;

  hipLaunchKernelGGL(k_prep, dim3((HH*HH + 24576 + 2048 + 1 + 255)/256), dim3(256), 0, stream, Wd, Wt, Wa, ws);
  hipLaunchKernelGGL(k_proj, dim3(BB*SS/64), dim3(256), 0, stream, hs, ad, ws);
  hipLaunchKernelGGL(k_gram, dim3(8,8,BB), dim3(256), 0, stream, ws, twp, awp, fbp, out_text, out_fus);
  hipLaunchKernelGGL(k_att0, dim3(BB), dim3(256), 0, stream, ws, amask, twp, awp, fbp);
  hipLaunchKernelGGL(k_pv, dim3(3,8,BB), dim3(256), 0, stream, hs, ws);
  hipLaunchKernelGGL(k_dense_ln, dim3(BB), dim3(256), 0, stream, ws, bd, lw, lb, out_h);
}

// Round 6
// 179.351 us; speedup vs baseline: 1.7022x; 1.3880x over previous
//
#include <hip/hip_runtime.h>
#include <math.h>

#define BB 32
#define SS 512
#define HH 768
#define FDD 64
#define PP 30

typedef __attribute__((ext_vector_type(8))) short short8v;
typedef __attribute__((ext_vector_type(4))) float f32x4;

// ws float offsets
#define O_TEXTF  0u        // fp32 text  [16384][32]
#define O_AUDF   524288u   // fp32 audio [16384][32]
#define O_ATT    1048576u  // 32*512 att weights
#define O_SCORE  1064960u  // 32*512 raw scores
#define O_FPART  1081344u  // 8*32*768 pv partials
#define O_HPART  1277952u  // 12*32*768 dense partials
#define O_WDT    1572864u  // 768*768 transposed W_dense
#define O_WTB    2162688u  // 24576 ushort (bf16 Wt frag-ordered)
#define O_WAB    2174976u  // 2048 ushort  (bf16 Wa frag-ordered)
#define O_TEXTB  2176000u  // bf16 text  [16384][32]
#define O_AUDB   2438144u  // bf16 audio [16384][32]
#define O_SUMSQ  2700288u  // 1

__device__ __forceinline__ unsigned short f2bf(float f){
  unsigned u = __float_as_uint(f);
  unsigned r = (u + 0x7fffu + ((u>>16)&1u)) >> 16;   // RNE
  return (unsigned short)r;
}
__device__ __forceinline__ float d4(const float4& a, const float4& b){
  return a.x*b.x + a.y*b.y + a.z*b.z + a.w*b.w;
}

// ---- prep: LDS-tiled WdT transpose (blocks 0..575), bf16 frag Wt/Wa (576..679), sumsq zero (680) ----
__global__ __launch_bounds__(256) void k_prep(const float* __restrict__ Wd,
    const float* __restrict__ Wt, const float* __restrict__ Wa, float* __restrict__ ws){
  const int bi = blockIdx.x, tid = threadIdx.x;
  if (bi < 576){
    __shared__ float L[32][33];
    const int tx = bi % 24, ty = bi / 24;
    const int lx = tid & 31, ly = tid >> 5;
    #pragma unroll
    for (int i = 0; i < 4; ++i)
      L[ly + i*8][lx] = Wd[(size_t)(ty*32 + ly + i*8)*HH + tx*32 + lx];
    __syncthreads();
    #pragma unroll
    for (int i = 0; i < 4; ++i)
      ws[O_WDT + (size_t)(tx*32 + ly + i*8)*HH + ty*32 + lx] = L[lx][ly + i*8];
  } else if (bi < 680){
    int idx = (bi - 576)*256 + tid;
    if (idx < 24576){
      int j = idx & 7, lane = (idx>>3) & 63, t = idx>>9;   // t = n*24+ks
      int n = t / 24, ks = t - n*24;
      int p = n*16 + (lane & 15);
      int k = ks*32 + ((lane>>4)<<3) + j;
      float v = (p < PP) ? Wt[p*HH + k] : 0.0f;
      ((unsigned short*)(ws + O_WTB))[idx] = f2bf(v);
    } else {
      int fa = idx - 24576;   // < 2048
      int j = fa & 7, lane = (fa>>3) & 63, t = fa>>9;      // t = n*2+ks
      int n = t>>1, ks = t & 1;
      int p = n*16 + (lane & 15);
      int k = ks*32 + ((lane>>4)<<3) + j;
      float v = (p < PP) ? Wa[p*FDD + k] : 0.0f;
      ((unsigned short*)(ws + O_WAB))[fa] = f2bf(v);
    }
  } else if (tid == 0){
    ws[O_SUMSQ] = 0.0f;
  }
}

// ---- projection via bf16 MFMA: 64 rows/block, 4 waves x 16 rows ----
__global__ __launch_bounds__(256) void k_proj(const float* __restrict__ hs,
    const float* __restrict__ ad, float* __restrict__ ws){
  __shared__ __align__(16) unsigned short Ast[64*32];   // frag-ordered bf16 A tile
  const int tid = threadIdx.x;
  const int lane = tid & 63, w = tid >> 6;
  const int rowbase = blockIdx.x * 64;
  const int tr = tid >> 2, tq = tid & 3;                // staging: row, k-quad
  const int wrunit = ((tr>>4)<<6) + (tr & 15) + (tq<<4);
  const short8v* WTB = (const short8v*)(ws + O_WTB);
  const short8v* WAB = (const short8v*)(ws + O_WAB);
  f32x4 accT0 = {0,0,0,0}, accT1 = {0,0,0,0};

  const float* hsr = hs + (size_t)(rowbase + tr)*HH + tq*8;
  float4 p0 = *(const float4*)hsr, p1 = *(const float4*)(hsr + 4);
  for (int ks = 0; ks < 24; ++ks){
    __syncthreads();   // previous iter's reads done
    uint4 pk;
    pk.x = f2bf(p0.x) | ((unsigned)f2bf(p0.y) << 16);
    pk.y = f2bf(p0.z) | ((unsigned)f2bf(p0.w) << 16);
    pk.z = f2bf(p1.x) | ((unsigned)f2bf(p1.y) << 16);
    pk.w = f2bf(p1.z) | ((unsigned)f2bf(p1.w) << 16);
    *(uint4*)&Ast[wrunit*8] = pk;
    if (ks < 23){ hsr += 32; p0 = *(const float4*)hsr; p1 = *(const float4*)(hsr + 4); }
    __syncthreads();
    short8v a = *(const short8v*)&Ast[(w*64 + lane)*8];
    short8v b0 = WTB[ks*64 + lane];
    short8v b1 = WTB[(24 + ks)*64 + lane];
    accT0 = __builtin_amdgcn_mfma_f32_16x16x32_bf16(a, b0, accT0, 0, 0, 0);
    accT1 = __builtin_amdgcn_mfma_f32_16x16x32_bf16(a, b1, accT1, 0, 0, 0);
  }

  f32x4 accA0 = {0,0,0,0}, accA1 = {0,0,0,0};
  for (int ks = 0; ks < 2; ++ks){
    const float* adr = ad + (size_t)(rowbase + tr)*FDD + ks*32 + tq*8;
    float4 q0 = *(const float4*)adr, q1 = *(const float4*)(adr + 4);
    __syncthreads();
    uint4 pk;
    pk.x = f2bf(q0.x) | ((unsigned)f2bf(q0.y) << 16);
    pk.y = f2bf(q0.z) | ((unsigned)f2bf(q0.w) << 16);
    pk.z = f2bf(q1.x) | ((unsigned)f2bf(q1.y) << 16);
    pk.w = f2bf(q1.z) | ((unsigned)f2bf(q1.w) << 16);
    *(uint4*)&Ast[wrunit*8] = pk;
    __syncthreads();
    short8v a = *(const short8v*)&Ast[(w*64 + lane)*8];
    accA0 = __builtin_amdgcn_mfma_f32_16x16x32_bf16(a, WAB[ks*64 + lane], accA0, 0, 0, 0);
    accA1 = __builtin_amdgcn_mfma_f32_16x16x32_bf16(a, WAB[(2 + ks)*64 + lane], accA1, 0, 0, 0);
  }

  // epilogue: C layout col=lane&15, row=(lane>>4)*4+r
  float* TEXTF = ws + O_TEXTF;
  float* AUDF  = ws + O_AUDF;
  unsigned short* TEXTB = (unsigned short*)(ws + O_TEXTB);
  unsigned short* AUDB  = (unsigned short*)(ws + O_AUDB);
  const int q4 = lane >> 4, pl = lane & 15;
  float sq = 0.0f;
  #pragma unroll
  for (int r = 0; r < 4; ++r){
    int row = rowbase + w*16 + q4*4 + r;
    float v0 = accT0[r], v1 = accT1[r];
    sq += v0*v0 + v1*v1;                    // p=30,31 exact zeros
    TEXTF[(size_t)row*32 + pl]      = v0;
    TEXTF[(size_t)row*32 + 16 + pl] = v1;
    TEXTB[(size_t)row*32 + pl]      = f2bf(v0);
    TEXTB[(size_t)row*32 + 16 + pl] = f2bf(v1);
    float a0 = accA0[r], a1 = accA1[r];
    AUDF[(size_t)row*32 + pl]      = a0;
    AUDF[(size_t)row*32 + 16 + pl] = a1;
    AUDB[(size_t)row*32 + pl]      = f2bf(a0);
    AUDB[(size_t)row*32 + 16 + pl] = f2bf(a1);
  }
  #pragma unroll
  for (int off = 32; off; off >>= 1) sq += __shfl_xor(sq, off);
  if (lane == 0) atomicAdd(ws + O_SUMSQ, sq);
}

// ---- gram via bf16 MFMA, K=32 (pad), no LDS; 64x64 tile per block ----
__global__ __launch_bounds__(256) void k_gram(const float* __restrict__ ws,
    const float* __restrict__ twp, const float* __restrict__ awp, const float* __restrict__ fbp,
    float* __restrict__ out_text, float* __restrict__ out_fus){
  const int tid = threadIdx.x, lane = tid & 63, w = tid >> 6;
  const int tt = blockIdx.x, st = blockIdx.y, b = blockIdx.z;
  const unsigned short* TEXTB = (const unsigned short*)(ws + O_TEXTB);
  const unsigned short* AUDB  = (const unsigned short*)(ws + O_AUDB);
  const int q4 = lane >> 4, pl = lane & 15;
  const size_t srow  = (size_t)b*SS + st*64 + w*16 + pl;
  const size_t trow0 = (size_t)b*SS + tt*64 + pl;
  short8v at = *(const short8v*)&TEXTB[srow*32 + q4*8];
  short8v aa = *(const short8v*)&AUDB [srow*32 + q4*8];
  f32x4 z = {0,0,0,0};
  f32x4 ct[4], ca[4];
  #pragma unroll
  for (int n = 0; n < 4; ++n){
    short8v bt = *(const short8v*)&TEXTB[(trow0 + n*16)*32 + q4*8];
    short8v ba = *(const short8v*)&AUDB [(trow0 + n*16)*32 + q4*8];
    ct[n] = __builtin_amdgcn_mfma_f32_16x16x32_bf16(at, bt, z, 0, 0, 0);
    ca[n] = __builtin_amdgcn_mfma_f32_16x16x32_bf16(aa, ba, z, 0, 0, 0);
  }
  const float inv_s = 1.0f / sqrtf(ws[O_SUMSQ]);
  const float tw = twp[0], aw = awp[0], fb = fbp[0];
  #pragma unroll
  for (int n = 0; n < 4; ++n){
    #pragma unroll
    for (int r = 0; r < 4; ++r){
      float t_ = fmaxf(ct[n][r]*inv_s, 0.0f);
      float a_ = fmaxf(ca[n][r], 0.0f);
      float f_ = fmaxf(tw*t_ + aw*a_ + fb, 0.0f);
      int sr = st*64 + w*16 + q4*4 + r;
      int tc = tt*64 + n*16 + pl;
      size_t o = ((size_t)b*SS + sr)*SS + tc;
      out_text[o] = t_;
      out_fus[o]  = f_;
    }
  }
}

// ---- row-0 raw scores (fp32): one thread per t ----
__global__ __launch_bounds__(256) void k_score(float* __restrict__ ws, const float* __restrict__ amask,
    const float* __restrict__ twp, const float* __restrict__ awp, const float* __restrict__ fbp){
  const int b = blockIdx.y, tid = threadIdx.x;
  const int t = blockIdx.x*256 + tid;
  __shared__ __align__(16) float t0[32], a0[32];
  const float* TEXTF = ws + O_TEXTF;
  const float* AUDF  = ws + O_AUDF;
  if (tid < 32){
    t0[tid] = TEXTF[(size_t)b*SS*32 + tid];
    a0[tid] = AUDF [(size_t)b*SS*32 + tid];
  }
  __syncthreads();
  const float inv_s = 1.0f / sqrtf(ws[O_SUMSQ]);
  const float tw = twp[0], aw = awp[0], fb = fbp[0];
  const float m0 = amask[(size_t)b*SS];
  const float4* t04 = (const float4*)t0;
  const float4* a04 = (const float4*)a0;
  const float4* tr = (const float4*)(TEXTF + ((size_t)b*SS + t)*32);
  const float4* ar = (const float4*)(AUDF  + ((size_t)b*SS + t)*32);
  float dt = 0.f, da = 0.f;
  #pragma unroll
  for (int q = 0; q < 8; ++q){ dt += d4(t04[q], tr[q]); da += d4(a04[q], ar[q]); }
  ws[O_SCORE + (size_t)b*SS + t] =
      tw*fmaxf(dt*inv_s, 0.f) + aw*fmaxf(da, 0.f) + fb + amask[(size_t)b*SS + t] + m0;
}

// ---- row-0 softmax from cached scores ----
__global__ __launch_bounds__(512) void k_soft(float* __restrict__ ws){
  const int b = blockIdx.x, tid = threadIdx.x;
  __shared__ float red[512];
  const float sv = ws[O_SCORE + (size_t)b*SS + tid];
  red[tid] = sv;
  __syncthreads();
  for (int s2 = 256; s2 > 0; s2 >>= 1){ if (tid < s2) red[tid] = fmaxf(red[tid], red[tid+s2]); __syncthreads(); }
  const float m = red[0];
  __syncthreads();
  const float e = __expf(sv - m);
  red[tid] = e;
  __syncthreads();
  for (int s2 = 256; s2 > 0; s2 >>= 1){ if (tid < s2) red[tid] += red[tid+s2]; __syncthreads(); }
  ws[O_ATT + (size_t)b*SS + tid] = e / red[0];
}

// ---- row-0 PV: (3 c-chunks, 8 t-chunks, 32 b) ----
__global__ __launch_bounds__(256) void k_pv(const float* __restrict__ hs, float* __restrict__ ws){
  const int tid = threadIdx.x;
  const int cx = blockIdx.x, th = blockIdx.y, b = blockIdx.z;
  __shared__ float a[64];
  if (tid < 64) a[tid] = ws[O_ATT + (size_t)b*SS + th*64 + tid];
  __syncthreads();
  const int c = cx*256 + tid;
  const float* hp = hs + ((size_t)b*SS + th*64)*HH + c;
  float acc = 0.f;
  #pragma unroll 8
  for (int t = 0; t < 64; ++t) acc += a[t]*hp[(size_t)t*HH];
  if (th == 0) acc += hs[(size_t)b*SS*HH + c];   // residual
  ws[O_FPART + ((size_t)th*BB + b)*HH + c] = acc;
}

// ---- dense split-K: block (kc, b) handles 64 c-values, all 768 outputs ----
__global__ __launch_bounds__(256) void k_dense(float* __restrict__ ws){
  const int kc = blockIdx.x, b = blockIdx.y, tid = threadIdx.x;
  __shared__ float fc[64];
  if (tid < 64){
    float s = 0.f;
    const int c = kc*64 + tid;
    #pragma unroll
    for (int th = 0; th < 8; ++th) s += ws[O_FPART + ((size_t)th*BB + b)*HH + c];
    fc[tid] = s;
  }
  __syncthreads();
  const float* Wp = ws + O_WDT + (size_t)(kc*64)*HH;
  float a0 = 0.f, a1 = 0.f, a2 = 0.f;
  #pragma unroll 8
  for (int i = 0; i < 64; ++i){
    const float fv = fc[i];
    const float* wr = Wp + (size_t)i*HH + tid;
    a0 += fv*wr[0];
    a1 += fv*wr[256];
    a2 += fv*wr[512];
  }
  float* hp = ws + O_HPART + ((size_t)kc*BB + b)*HH;
  hp[tid]       = a0;
  hp[tid + 256] = a1;
  hp[tid + 512] = a2;
}

// ---- LN over 12 dense partials ----
__global__ __launch_bounds__(256) void k_ln(const float* __restrict__ ws,
    const float* __restrict__ bd, const float* __restrict__ lw, const float* __restrict__ lb,
    float* __restrict__ out){
  const int b = blockIdx.x, tid = threadIdx.x;
  __shared__ float red[256];
  float a0 = bd[tid], a1 = bd[tid+256], a2 = bd[tid+512];
  #pragma unroll
  for (int kc = 0; kc < 12; ++kc){
    const float* hp = ws + O_HPART + ((size_t)kc*BB + b)*HH;
    a0 += hp[tid];
    a1 += hp[tid + 256];
    a2 += hp[tid + 512];
  }
  red[tid] = a0 + a1 + a2;
  __syncthreads();
  for (int s2 = 128; s2 > 0; s2 >>= 1){ if (tid < s2) red[tid] += red[tid+s2]; __syncthreads(); }
  const float u = red[0]*(1.0f/HH);
  __syncthreads();
  const float d0 = a0-u, d1 = a1-u, d2 = a2-u;
  red[tid] = d0*d0 + d1*d1 + d2*d2;
  __syncthreads();
  for (int s2 = 128; s2 > 0; s2 >>= 1){ if (tid < s2) red[tid] += red[tid+s2]; __syncthreads(); }
  const float isd = 1.0f / sqrtf(red[0]*(1.0f/HH) + 1e-12f);
  out[(size_t)b*HH + tid]     = lw[tid]    *d0*isd + lb[tid];
  out[(size_t)b*HH + tid+256] = lw[tid+256]*d1*isd + lb[tid+256];
  out[(size_t)b*HH + tid+512] = lw[tid+512]*d2*isd + lb[tid+512];
}

extern "C" void kernel_launch(void* const* d_in, const int* in_sizes, int n_in,
                              void* d_out, int out_size, void* d_ws, size_t ws_size,
                              hipStream_t stream){
  const float* hs    = (const float*)d_in[0];
  const float* ad    = (const float*)d_in[1];
  const float* amask = (const float*)d_in[2];
  const float* Wt    = (const float*)d_in[3];
  const float* Wa    = (const float*)d_in[4];
  const float* twp   = (const float*)d_in[5];
  const float* awp   = (const float*)d_in[6];
  const float* fbp   = (const float*)d_in[7];
  const float* Wd    = (const float*)d_in[8];
  const float* bd    = (const float*)d_in[9];
  const float* lw    = (const float*)d_in[10];
  const float* lb    = (const float*)d_in[11];
  float* out = (float*)d_out;
  float* ws  = (float*)d_ws;
  float* out_h    = out;
  float* out_text = out + (size_t)BB*HH;
  float* out_fus  = out_text + (size_t)BB*SS*SS;

  hipLaunchKernelGGL(k_prep, dim3(681), dim3(256), 0, stream, Wd, Wt, Wa, ws);
  hipLaunchKernelGGL(k_proj, dim3(BB*SS/64), dim3(256), 0, stream, hs, ad, ws);
  hipLaunchKernelGGL(k_gram, dim3(8,8,BB), dim3(256), 0, stream, ws, twp, awp, fbp, out_text, out_fus);
  hipLaunchKernelGGL(k_score, dim3(2,BB), dim3(256), 0, stream, ws, amask, twp, awp, fbp);
  hipLaunchKernelGGL(k_soft, dim3(BB), dim3(512), 0, stream, ws);
  hipLaunchKernelGGL(k_pv, dim3(3,8,BB), dim3(256), 0, stream, hs, ws);
  hipLaunchKernelGGL(k_dense, dim3(12,BB), dim3(256), 0, stream, ws);
  hipLaunchKernelGGL(k_ln, dim3(BB), dim3(256), 0, stream, ws, bd, lw, lb, out_h);
}